// Round 2
// baseline (1338.425 us; speedup 1.0000x reference)
//
#include <hip/hip_runtime.h>
#include <stdint.h>

#define TOPK 20
#define BLK 256
#define CAP 2048
#define DELTA 2.0f
#define LSTRIDE 21
#define L2E 1.4426950408889634f
#define IGNORE_INDEX (-100)

typedef float f4v __attribute__((ext_vector_type(4)));

__device__ __forceinline__ unsigned fkey(float x) {
  unsigned b = __float_as_uint(x);
  return (b & 0x80000000u) ? ~b : (b | 0x80000000u);
}
__device__ __forceinline__ float funkey(unsigned k) {
  unsigned b = (k & 0x80000000u) ? (k & 0x7FFFFFFFu) : ~k;
  return __uint_as_float(b);
}

// sorted-descending top-20 insert (fully unrolled, registers only)
__device__ __forceinline__ void ins20(float (&tv)[TOPK], float c) {
  if (c > tv[TOPK - 1]) {
#pragma unroll
    for (int j = 0; j < TOPK; ++j) {
      float hi = fmaxf(tv[j], c);
      c = fminf(tv[j], c);
      tv[j] = hi;
    }
  }
}

// merge two sorted-desc 20-lists (padded to 21 with -inf) -> top-20 into O
__device__ __forceinline__ void merge2(const float* A, const float* B, float* O) {
  int i = 1, j = 1;
  float a = A[0], b = B[0];
#pragma unroll
  for (int k = 0; k < TOPK; ++k) {
    if (a >= b) { O[k] = a; a = A[i]; ++i; }
    else        { O[k] = b; b = B[j]; ++j; }
  }
}

// merge 64 lists living in bufA (stride LSTRIDE, pad slot 20 = -inf).
// ALL 256 threads must call (contains barriers). Returns pointer to result list.
__device__ float* merge64(int tid, float* bufA, float* bufB) {
  float* srcb = bufA;
  float* dstb = bufB;
  for (int s = 32; s >= 1; s >>= 1) {
    __syncthreads();
    if (tid < s) {
      merge2(srcb + tid * LSTRIDE, srcb + (tid + s) * LSTRIDE, dstb + tid * LSTRIDE);
      dstb[tid * LSTRIDE + TOPK] = -INFINITY;
    }
    float* t = srcb; srcb = dstb; dstb = t;
  }
  __syncthreads();
  return srcb;
}

__global__ __launch_bounds__(BLK) void eaft_ce_kernel(
    const float* __restrict__ src, const int* __restrict__ tgt,
    float* __restrict__ acc, int V) {
  __shared__ float s_cand[CAP];
  __shared__ float s_bufA[64 * LSTRIDE];
  __shared__ float s_bufB[64 * LSTRIDE];
  __shared__ float s_wm[4];
  __shared__ float s_wl[4];
  __shared__ unsigned s_maxkey;
  __shared__ int s_cnt;
  __shared__ int s_slow;

  const int tid = threadIdx.x;
  const int row = blockIdx.x;
  if (tid == 0) { s_maxkey = 0u; s_cnt = 0; s_slow = 0; }
  __syncthreads();

  const size_t rowbase = (size_t)row * (size_t)V;
  const float* arow = src + rowbase;
  const int head = (int)((4 - (rowbase & 3)) & 3);
  const f4v* vp = (const f4v*)(arow + head);
  const int nvec = (V - head) >> 2;
  const int tail = V - head - (nvec << 2);

  // ---------- peel: first vec batch + head/tail scalars (prime block max) ----------
  f4v pv = {-INFINITY, -INFINITY, -INFINITY, -INFINITY};
  if (tid < nvec) pv = vp[tid];
  float ex = -INFINITY;
  if (tid < head) ex = arow[tid];
  else if (tid >= 64 && tid < 64 + tail) ex = arow[head + (nvec << 2) + (tid - 64)];

  float pmax = fmaxf(fmaxf(fmaxf(pv.x, pv.y), fmaxf(pv.z, pv.w)), ex);
  if (pmax > -INFINITY) atomicMax(&s_maxkey, fkey(pmax));
  __syncthreads();  // block max primed with ~1024 samples

  // lane's LSE is referenced to its view `bm` of the block max (only grows).
  // exp2 args stay small: bm >= max of first ~1024 N(0,1) samples (~3.2s),
  // true max ~4.5s -> exp2((x-bm)*L2E) <= ~e^1.9.
  float bm = funkey(s_maxkey);
  float lmax = bm;            // lane's known ceiling (avoid redundant atomic posts)
  float cexp = -bm * L2E;
  float l0 = 0.f, l1 = 0.f, l2 = 0.f, l3 = 0.f;
  float T = bm - DELTA;

  // per-element processing: LSE accumulate + thresholded candidate capture.
  // completeness invariant: a skipped x satisfies x < bm_view - DELTA <= tmax - DELTA,
  // so the final check R[19] >= tmax - DELTA proves the true top-20 was captured.
  auto proc4 = [&](const f4v v, float& lacc) {
    float vv[4] = {v.x, v.y, v.z, v.w};
#pragma unroll
    for (int q = 0; q < 4; ++q) {
      float x = vv[q];
      lacc += exp2f(fmaf(x, L2E, cexp));
      if (x >= T) {  // any new max satisfies x >= T, so max-post nests here
        int p = atomicAdd(&s_cnt, 1);
        if (p < CAP) s_cand[p] = x;
        if (x > lmax) { lmax = x; atomicMax(&s_maxkey, fkey(x)); }
      }
    }
  };
  auto poll = [&]() {
    float nb = funkey(*(volatile unsigned*)&s_maxkey);
    if (nb > bm) {            // rare: rescale once per batch, not per element
      float r = exp2f((bm - nb) * L2E);
      l0 *= r; l1 *= r; l2 *= r; l3 *= r;
      bm = nb; cexp = -bm * L2E; T = bm - DELTA;
      if (nb > lmax) lmax = nb;
    }
  };

  // retroactive pass over peel elements: accumulate LSE + candidate test
  {
    float vals[5] = {pv.x, pv.y, pv.z, pv.w, ex};
#pragma unroll
    for (int q = 0; q < 5; ++q) {
      float x = vals[q];
      l0 += exp2f(fmaf(x, L2E, cexp));  // exp2(-inf) = 0 for pad lanes
      if (x >= T) {
        int p = atomicAdd(&s_cnt, 1);
        if (p < CAP) s_cand[p] = x;
        if (x > lmax) { lmax = x; atomicMax(&s_maxkey, fkey(x)); }
      }
    }
  }

  // ---------- main loop: 4 float4/iter, explicit register double-buffer ----------
  // Current batch lives in c0..c3 while next batch n0..n3 is IN FLIGHT -> the only
  // vmcnt wait is at the rotation, giving loads a full body (+ cross-wave TLP) to land.
  const int base = BLK + tid;          // peel consumed vec indices [0, BLK)
  const int rem0 = nvec - BLK;
  const int nfull = rem0 > 0 ? rem0 / (4 * BLK) : 0;

  if (nfull > 0) {
    f4v c0 = vp[base];
    f4v c1 = vp[base + BLK];
    f4v c2 = vp[base + 2 * BLK];
    f4v c3 = vp[base + 3 * BLK];
    for (int t = 1; t < nfull; ++t) {
      const int nx = base + t * (4 * BLK);
      f4v n0 = vp[nx];
      f4v n1 = vp[nx + BLK];
      f4v n2 = vp[nx + 2 * BLK];
      f4v n3 = vp[nx + 3 * BLK];
      poll();
      proc4(c0, l0); proc4(c1, l1); proc4(c2, l2); proc4(c3, l3);
      c0 = n0; c1 = n1; c2 = n2; c3 = n3;
    }
    poll();
    proc4(c0, l0); proc4(c1, l1); proc4(c2, l2); proc4(c3, l3);
  }
  // remainder (at most 4 float4 per thread, unpipelined)
  for (int i2 = base + nfull * (4 * BLK); i2 < nvec; i2 += BLK) {
    f4v a = vp[i2];
    poll();
    proc4(a, l0);
  }

  // ---------- barrier-free wave LSE reduce, then 4-entry cross-wave combine ----------
  {
    float m = bm, l = (l0 + l1) + (l2 + l3);  // lanes may hold different bm views
#pragma unroll
    for (int off = 32; off > 0; off >>= 1) {
      float om = __shfl_down(m, off);
      float ol = __shfl_down(l, off);
      float M = fmaxf(m, om);
      l = l * exp2f((m - M) * L2E) + ol * exp2f((om - M) * L2E);
      m = M;
    }
    if ((tid & 63) == 0) { s_wm[tid >> 6] = m; s_wl[tid >> 6] = l; }
  }
  __syncthreads();  // also makes s_cnt / s_cand / s_maxkey posts visible

  // ---------- top-20 selection from candidates (wave 0 builds 64 lists) ----------
  const int cnt_raw = s_cnt;
  const int C = cnt_raw < CAP ? cnt_raw : CAP;
  if (tid < 64) {
    float tv[TOPK];
#pragma unroll
    for (int j = 0; j < TOPK; ++j) tv[j] = -INFINITY;
    for (int k = tid; k < C; k += 64) ins20(tv, s_cand[k]);
#pragma unroll
    for (int j = 0; j < TOPK; ++j) s_bufA[tid * LSTRIDE + j] = tv[j];
    s_bufA[tid * LSTRIDE + TOPK] = -INFINITY;
  }
  float* R = merge64(tid, s_bufA, s_bufB);

  // ---------- verification vs TRUE row max; rare exact slow path ----------
  const float tmax = funkey(s_maxkey);  // final value: all posts fenced by barriers
  if (tid == 0)
    s_slow = (cnt_raw > CAP || R[TOPK - 1] < tmax - DELTA) ? 1 : 0;
  __syncthreads();

  if (s_slow) {
    float tv[TOPK];
#pragma unroll
    for (int j = 0; j < TOPK; ++j) tv[j] = -INFINITY;
    for (int e = tid; e < V; e += BLK) ins20(tv, arow[e]);
    for (int r = 0; r < 4; ++r) {
      __syncthreads();
      if ((tid >> 6) == r) {
        int lane = tid & 63;
#pragma unroll
        for (int j = 0; j < TOPK; ++j) s_bufA[lane * LSTRIDE + j] = tv[j];
        s_bufA[lane * LSTRIDE + TOPK] = -INFINITY;
      }
      float* Rr = merge64(tid, s_bufA, s_bufB);
      if (tid == 0) {
#pragma unroll
        for (int j = 0; j < TOPK; ++j) s_cand[r * LSTRIDE + j] = Rr[j];
        s_cand[r * LSTRIDE + TOPK] = -INFINITY;
      }
      __syncthreads();
    }
    if (tid == 0) {
      merge2(s_cand + 0 * LSTRIDE, s_cand + 1 * LSTRIDE, s_bufA);
      s_bufA[TOPK] = -INFINITY;
      merge2(s_cand + 2 * LSTRIDE, s_cand + 3 * LSTRIDE, s_bufA + LSTRIDE);
      s_bufA[LSTRIDE + TOPK] = -INFINITY;
      merge2(s_bufA, s_bufA + LSTRIDE, s_bufB);
    }
  }
  __syncthreads();

  // ---------- entropy weight + loss contribution (thread 0) ----------
  if (tid == 0) {
    const float* W = s_slow ? s_bufB : R;
    int t = tgt[row];
    if (t != IGNORE_INDEX) {
      // combine the 4 per-wave LSE partials
      float M = fmaxf(fmaxf(s_wm[0], s_wm[1]), fmaxf(s_wm[2], s_wm[3]));
      float S = 0.f;
#pragma unroll
      for (int k = 0; k < 4; ++k) S += s_wl[k] * exp2f((s_wm[k] - M) * L2E);
      const float lse_row = M + logf(S);

      float tl = arow[t];
      float loss = lse_row - tl;
      float m0 = W[0];
      float S1 = 0.f, Sv = 0.f;
#pragma unroll
      for (int k2 = 0; k2 < TOPK; ++k2) {
        float v = W[k2];
        float e = exp2f((v - m0) * L2E);
        S1 += e;
        Sv += v * e;
      }
      float ent = (m0 + logf(S1)) - Sv / S1;
      float w = ent * (1.0f / 3.0f);
      atomicAdd(&acc[0], w * loss);
      atomicAdd(&acc[1], 1.0f);
    }
  }
}

__global__ void finalize_kernel(const float* __restrict__ acc, float* __restrict__ out) {
  out[0] = acc[0] / acc[1];
}

extern "C" void kernel_launch(void* const* d_in, const int* in_sizes, int n_in,
                              void* d_out, int out_size, void* d_ws, size_t ws_size,
                              hipStream_t stream) {
  const float* src = (const float*)d_in[0];
  const int* tgt = (const int*)d_in[1];
  const int NV = in_sizes[0];
  const int n = in_sizes[1];
  const int V = NV / n;
  float* ws = (float*)d_ws;
  hipMemsetAsync(ws, 0, 2 * sizeof(float), stream);
  eaft_ce_kernel<<<n, BLK, 0, stream>>>(src, tgt, ws, V);
  finalize_kernel<<<1, 1, 0, stream>>>(ws, (float*)d_out);
}

// Round 3
// 1128.030 us; speedup vs baseline: 1.1865x; 1.1865x over previous
//
#include <hip/hip_runtime.h>
#include <stdint.h>

#define TOPK 20
#define BLK 256
#define CAP 4096
#define PEEL 4
#define DELTA 2.0f
#define LSTRIDE 21
#define L2E 1.4426950408889634f
#define IGNORE_INDEX (-100)

typedef float f4v __attribute__((ext_vector_type(4)));

__device__ __forceinline__ unsigned fkey(float x) {
  unsigned b = __float_as_uint(x);
  return (b & 0x80000000u) ? ~b : (b | 0x80000000u);
}
__device__ __forceinline__ float funkey(unsigned k) {
  unsigned b = (k & 0x80000000u) ? (k & 0x7FFFFFFFu) : ~k;
  return __uint_as_float(b);
}

// sorted-descending top-20 insert (fully unrolled, registers only)
__device__ __forceinline__ void ins20(float (&tv)[TOPK], float c) {
  if (c > tv[TOPK - 1]) {
#pragma unroll
    for (int j = 0; j < TOPK; ++j) {
      float hi = fmaxf(tv[j], c);
      c = fminf(tv[j], c);
      tv[j] = hi;
    }
  }
}

// merge two sorted-desc 20-lists (padded to 21 with -inf) -> top-20 into O
__device__ __forceinline__ void merge2(const float* A, const float* B, float* O) {
  int i = 1, j = 1;
  float a = A[0], b = B[0];
#pragma unroll
  for (int k = 0; k < TOPK; ++k) {
    if (a >= b) { O[k] = a; a = A[i]; ++i; }
    else        { O[k] = b; b = B[j]; ++j; }
  }
}

// merge 64 lists living in bufA (stride LSTRIDE, pad slot 20 = -inf).
// ALL 256 threads must call (contains barriers). Returns pointer to result list.
__device__ float* merge64(int tid, float* bufA, float* bufB) {
  float* srcb = bufA;
  float* dstb = bufB;
  for (int s = 32; s >= 1; s >>= 1) {
    __syncthreads();
    if (tid < s) {
      merge2(srcb + tid * LSTRIDE, srcb + (tid + s) * LSTRIDE, dstb + tid * LSTRIDE);
      dstb[tid * LSTRIDE + TOPK] = -INFINITY;
    }
    float* t = srcb; srcb = dstb; dstb = t;
  }
  __syncthreads();
  return srcb;
}

__global__ __launch_bounds__(BLK) void eaft_ce_kernel(
    const float* __restrict__ src, const int* __restrict__ tgt,
    float* __restrict__ acc, int V) {
  __shared__ float s_cand[CAP];
  __shared__ float s_bufA[64 * LSTRIDE];
  __shared__ float s_bufB[64 * LSTRIDE];
  __shared__ float s_wm[4];
  __shared__ float s_wl[4];
  __shared__ unsigned s_maxkey;
  __shared__ int s_cnt;
  __shared__ int s_slow;

  const int tid = threadIdx.x;
  const int row = blockIdx.x;
  if (tid == 0) { s_maxkey = 0u; s_cnt = 0; s_slow = 0; }
  __syncthreads();

  const size_t rowbase = (size_t)row * (size_t)V;
  const float* arow = src + rowbase;
  const int head = (int)((4 - (rowbase & 3)) & 3);
  const f4v* vp = (const f4v*)(arow + head);
  const int nvec = (V - head) >> 2;
  const int tail = V - head - (nvec << 2);

  // ---------- peel: PEEL vec batches + head/tail scalars (prime block max) ----------
  // 4096 samples -> primed max ~3.49 for N(0,1): initial capture rate ~0.068,
  // keeping total candidates ~1700 << CAP (slow path stays rare).
  f4v pv[PEEL];
#pragma unroll
  for (int p = 0; p < PEEL; ++p) {
    const int idx = p * BLK + tid;
    f4v v = {-INFINITY, -INFINITY, -INFINITY, -INFINITY};
    if (idx < nvec) v = vp[idx];
    pv[p] = v;
  }
  float ex = -INFINITY;
  if (tid < head) ex = arow[tid];
  else if (tid >= 64 && tid < 64 + tail) ex = arow[head + (nvec << 2) + (tid - 64)];

  float pmax = ex;
#pragma unroll
  for (int p = 0; p < PEEL; ++p)
    pmax = fmaxf(pmax, fmaxf(fmaxf(pv[p].x, pv[p].y), fmaxf(pv[p].z, pv[p].w)));
  if (pmax > -INFINITY) atomicMax(&s_maxkey, fkey(pmax));
  __syncthreads();  // block max primed with ~4096 samples

  // lane's LSE is referenced to its view `bm` of the block max (only grows).
  float bm = funkey(s_maxkey);
  float lmax = bm;            // lane's known ceiling (avoid redundant atomic posts)
  float cexp = -bm * L2E;
  float l0 = 0.f, l1 = 0.f;
  float T = bm - DELTA;

  // per-element processing: LSE accumulate + thresholded candidate capture.
  // completeness invariant: a skipped x satisfies x < bm_view - DELTA <= tmax - DELTA,
  // so the final check R[19] >= tmax - DELTA proves the true top-20 was captured.
  auto proc4 = [&](const f4v v, float& lacc) {
    float vv[4] = {v.x, v.y, v.z, v.w};
#pragma unroll
    for (int q = 0; q < 4; ++q) {
      float x = vv[q];
      lacc += exp2f(fmaf(x, L2E, cexp));
      if (x >= T) {  // any new max satisfies x >= T, so max-post nests here
        int p = atomicAdd(&s_cnt, 1);
        if (p < CAP) s_cand[p] = x;
        if (x > lmax) { lmax = x; atomicMax(&s_maxkey, fkey(x)); }
      }
    }
  };
  auto poll = [&]() {
    float nb = funkey(*(volatile unsigned*)&s_maxkey);
    if (nb > bm) {            // rare: rescale once per batch, not per element
      float r = exp2f((bm - nb) * L2E);
      l0 *= r; l1 *= r;
      bm = nb; cexp = -bm * L2E; T = bm - DELTA;
      if (nb > lmax) lmax = nb;
    }
  };

  // retroactive pass over peel elements: accumulate LSE + candidate test
  {
#pragma unroll
    for (int p = 0; p < PEEL; ++p) proc4(pv[p], l0);
    float x = ex;
    l0 += exp2f(fmaf(x, L2E, cexp));  // exp2(-inf) = 0 for pad lanes
    if (x >= T) {
      int pq = atomicAdd(&s_cnt, 1);
      if (pq < CAP) s_cand[pq] = x;
      if (x > lmax) { lmax = x; atomicMax(&s_maxkey, fkey(x)); }
    }
  }

  // ---------- main loop: 2 float4/iter, prefetch pinned by sched_barrier ----------
  // Next iteration's loads are ISSUED before this iteration's body; sched_barrier(0)
  // stops the backend scheduler from sinking them to their use point (the round-2
  // failure mode: VGPR_Count=28 proved the pipeline was compiled away).
  int i = PEEL * BLK + tid;
  const int rem0 = nvec - PEEL * BLK;
  const int nfull = rem0 > 0 ? rem0 / (2 * BLK) : 0;

  if (nfull > 0) {
    f4v c0 = vp[i];
    f4v c1 = vp[i + BLK];
    for (int t = 1; t < nfull; ++t) {
      const f4v n0 = vp[i + 2 * BLK];
      const f4v n1 = vp[i + 3 * BLK];
      __builtin_amdgcn_sched_barrier(0);  // pin prefetch issue before the body
      poll();
      proc4(c0, l0); proc4(c1, l1);
      c0 = n0; c1 = n1;
      i += 2 * BLK;
    }
    poll();
    proc4(c0, l0); proc4(c1, l1);
    i += 2 * BLK;
  }
  // remainder (at most 2 float4 per thread, unpipelined)
  for (; i < nvec; i += BLK) {
    f4v a = vp[i];
    poll();
    proc4(a, l0);
  }

  // ---------- barrier-free wave LSE reduce, then 4-entry cross-wave combine ----------
  {
    float m = bm, l = l0 + l1;  // lanes may hold different bm views
#pragma unroll
    for (int off = 32; off > 0; off >>= 1) {
      float om = __shfl_down(m, off);
      float ol = __shfl_down(l, off);
      float M = fmaxf(m, om);
      l = l * exp2f((m - M) * L2E) + ol * exp2f((om - M) * L2E);
      m = M;
    }
    if ((tid & 63) == 0) { s_wm[tid >> 6] = m; s_wl[tid >> 6] = l; }
  }
  __syncthreads();  // also makes s_cnt / s_cand / s_maxkey posts visible

  // ---------- top-20 selection from candidates (wave 0 builds 64 lists) ----------
  const int cnt_raw = s_cnt;
  const int C = cnt_raw < CAP ? cnt_raw : CAP;
  if (tid < 64) {
    float tv[TOPK];
#pragma unroll
    for (int j = 0; j < TOPK; ++j) tv[j] = -INFINITY;
    for (int k = tid; k < C; k += 64) ins20(tv, s_cand[k]);
#pragma unroll
    for (int j = 0; j < TOPK; ++j) s_bufA[tid * LSTRIDE + j] = tv[j];
    s_bufA[tid * LSTRIDE + TOPK] = -INFINITY;
  }
  float* R = merge64(tid, s_bufA, s_bufB);

  // ---------- verification vs TRUE row max; rare exact slow path ----------
  const float tmax = funkey(s_maxkey);  // final value: all posts fenced by barriers
  if (tid == 0)
    s_slow = (cnt_raw > CAP || R[TOPK - 1] < tmax - DELTA) ? 1 : 0;
  __syncthreads();

  if (s_slow) {
    float tv[TOPK];
#pragma unroll
    for (int j = 0; j < TOPK; ++j) tv[j] = -INFINITY;
    for (int e = tid; e < V; e += BLK) ins20(tv, arow[e]);
    for (int r = 0; r < 4; ++r) {
      __syncthreads();
      if ((tid >> 6) == r) {
        int lane = tid & 63;
#pragma unroll
        for (int j = 0; j < TOPK; ++j) s_bufA[lane * LSTRIDE + j] = tv[j];
        s_bufA[lane * LSTRIDE + TOPK] = -INFINITY;
      }
      float* Rr = merge64(tid, s_bufA, s_bufB);
      if (tid == 0) {
#pragma unroll
        for (int j = 0; j < TOPK; ++j) s_cand[r * LSTRIDE + j] = Rr[j];
        s_cand[r * LSTRIDE + TOPK] = -INFINITY;
      }
      __syncthreads();
    }
    if (tid == 0) {
      merge2(s_cand + 0 * LSTRIDE, s_cand + 1 * LSTRIDE, s_bufA);
      s_bufA[TOPK] = -INFINITY;
      merge2(s_cand + 2 * LSTRIDE, s_cand + 3 * LSTRIDE, s_bufA + LSTRIDE);
      s_bufA[LSTRIDE + TOPK] = -INFINITY;
      merge2(s_bufA, s_bufA + LSTRIDE, s_bufB);
    }
  }
  __syncthreads();

  // ---------- entropy weight + loss contribution (thread 0) ----------
  if (tid == 0) {
    const float* W = s_slow ? s_bufB : R;
    int t = tgt[row];
    if (t != IGNORE_INDEX) {
      // combine the 4 per-wave LSE partials
      float M = fmaxf(fmaxf(s_wm[0], s_wm[1]), fmaxf(s_wm[2], s_wm[3]));
      float S = 0.f;
#pragma unroll
      for (int k = 0; k < 4; ++k) S += s_wl[k] * exp2f((s_wm[k] - M) * L2E);
      const float lse_row = M + logf(S);

      float tl = arow[t];
      float loss = lse_row - tl;
      float m0 = W[0];
      float S1 = 0.f, Sv = 0.f;
#pragma unroll
      for (int k2 = 0; k2 < TOPK; ++k2) {
        float v = W[k2];
        float e = exp2f((v - m0) * L2E);
        S1 += e;
        Sv += v * e;
      }
      float ent = (m0 + logf(S1)) - Sv / S1;
      float w = ent * (1.0f / 3.0f);
      atomicAdd(&acc[0], w * loss);
      atomicAdd(&acc[1], 1.0f);
    }
  }
}

__global__ void finalize_kernel(const float* __restrict__ acc, float* __restrict__ out) {
  out[0] = acc[0] / acc[1];
}

extern "C" void kernel_launch(void* const* d_in, const int* in_sizes, int n_in,
                              void* d_out, int out_size, void* d_ws, size_t ws_size,
                              hipStream_t stream) {
  const float* src = (const float*)d_in[0];
  const int* tgt = (const int*)d_in[1];
  const int NV = in_sizes[0];
  const int n = in_sizes[1];
  const int V = NV / n;
  float* ws = (float*)d_ws;
  hipMemsetAsync(ws, 0, 2 * sizeof(float), stream);
  eaft_ce_kernel<<<n, BLK, 0, stream>>>(src, tgt, ws, V);
  finalize_kernel<<<1, 1, 0, stream>>>(ws, (float*)d_out);
}